// Round 1
// baseline (1742.882 us; speedup 1.0000x reference)
//
#include <hip/hip_runtime.h>
#include <hip/hip_bf16.h>

constexpr int D_ = 128;
constexpr int DK_ = 16;
constexpr int TBL = 4096;

// ---------------- K_detect: is edge_index int64 (high words all zero) or int32? ----------------
__global__ void k_detect(const int* __restrict__ ei, int* __restrict__ flag) {
    __shared__ int sor;
    if (threadIdx.x == 0) sor = 0;
    __syncthreads();
    int v = 0;
    for (int k = threadIdx.x; k < 1024; k += blockDim.x) v |= ei[2 * k + 1];
    atomicOr(&sor, v);
    __syncthreads();
    if (threadIdx.x == 0) flag[0] = (sor == 0) ? 1 : 0;  // 1 => int64 layout
}

__device__ __forceinline__ void load_edge(const int* __restrict__ ei, int E, int f64,
                                          int e, int& s, int& dd) {
    if (f64) { s = ei[2 * e]; dd = ei[2 * E + 2 * e]; }
    else     { s = ei[e];     dd = ei[E + e]; }
}
__device__ __forceinline__ int load_src(const int* __restrict__ ei, int E, int f64, int e) {
    return f64 ? ei[2 * e] : ei[e];
}

// ---------------- K0: transpose W into WT[384][128], biases into BB[384] ----------------
__global__ void k_wprep(const float* __restrict__ Wq, const float* __restrict__ bq,
                        const float* __restrict__ Wk, const float* __restrict__ bk,
                        const float* __restrict__ Wv, const float* __restrict__ bv,
                        float* __restrict__ WT, float* __restrict__ BB) {
    int idx = blockIdx.x * blockDim.x + threadIdx.x;
    int total = 384 * 128;
    for (int i = idx; i < total; i += gridDim.x * blockDim.x) {
        int c = i >> 7;        // 0..383
        int d = i & 127;
        int m = c >> 7;        // 0:q 1:k 2:v
        int cl = c & 127;
        int h = cl >> 4, kk = cl & 15;
        const float* W = (m == 0) ? Wq : ((m == 1) ? Wk : Wv);
        WT[i] = W[(h * D_ + d) * DK_ + kk];
    }
    if (idx < 384) {
        int m = idx >> 7, cl = idx & 127;
        const float* b = (m == 0) ? bq : ((m == 1) ? bk : bv);
        BB[idx] = b[cl];
    }
}

// ---------------- K1: fused LayerNorm + 3 projections ----------------
__global__ __launch_bounds__(384)
void k_ln_proj(const float* __restrict__ x, const float* __restrict__ WT,
               const float* __restrict__ BB,
               float* __restrict__ qn, float* __restrict__ kn, float* __restrict__ vn,
               int N) {
    __shared__ float xs[16][128];
    int tid = threadIdx.x;
    int row0 = blockIdx.x * 16;

    for (int i = tid; i < 16 * 128; i += 384) {
        int r = i >> 7, d = i & 127;
        int gr = row0 + r;
        xs[r][d] = (gr < N) ? x[(size_t)gr * 128 + d] : 0.0f;
    }
    __syncthreads();

    if (tid < 256) {
        int r = tid >> 4, i = tid & 15;
        float v[8];
        float s = 0.f;
        #pragma unroll
        for (int k = 0; k < 8; ++k) { v[k] = xs[r][i * 8 + k]; s += v[k]; }
        s += __shfl_xor(s, 1); s += __shfl_xor(s, 2);
        s += __shfl_xor(s, 4); s += __shfl_xor(s, 8);
        float mu = s * (1.0f / 128.0f);
        float s2 = 0.f;
        #pragma unroll
        for (int k = 0; k < 8; ++k) { float dv = v[k] - mu; s2 += dv * dv; }
        s2 += __shfl_xor(s2, 1); s2 += __shfl_xor(s2, 2);
        s2 += __shfl_xor(s2, 4); s2 += __shfl_xor(s2, 8);
        float rs = rsqrtf(s2 * (1.0f / 128.0f) + 1e-5f);
        #pragma unroll
        for (int k = 0; k < 8; ++k) xs[r][i * 8 + k] = (v[k] - mu) * rs;
    }
    __syncthreads();

    // 4 rows x 4 cols per thread; 384 threads cover 16 rows x 384 cols
    int cg = tid % 96, rg = tid / 96;
    int c0 = cg * 4, r0 = rg * 4;
    float acc[4][4] = {};
    const float4* WT4 = (const float4*)WT;
    for (int d = 0; d < 128; d += 4) {
        float4 w[4];
        #pragma unroll
        for (int c = 0; c < 4; ++c) w[c] = WT4[(c0 + c) * 32 + (d >> 2)];
        #pragma unroll
        for (int r = 0; r < 4; ++r) {
            float4 xv = *(const float4*)&xs[r0 + r][d];
            #pragma unroll
            for (int c = 0; c < 4; ++c)
                acc[r][c] += xv.x * w[c].x + xv.y * w[c].y + xv.z * w[c].z + xv.w * w[c].w;
        }
    }
    #pragma unroll
    for (int c = 0; c < 4; ++c) {
        int cc = c0 + c;
        int m = cc >> 7, cl = cc & 127;
        float bb = BB[cc];
        float* dst = (m == 0) ? qn : ((m == 1) ? kn : vn);
        #pragma unroll
        for (int r = 0; r < 4; ++r) {
            int gr = row0 + r0 + r;
            if (gr < N) dst[(size_t)gr * 128 + cl] = acc[r][c] + bb;
        }
    }
}

// ---------------- K2: degree over senders ----------------
__global__ void k_deg(const int* __restrict__ ei, const float* __restrict__ w,
                      const int* __restrict__ flag, float* __restrict__ deg, int E) {
    int f64 = flag[0];
    int i = blockIdx.x * blockDim.x + threadIdx.x;
    int stride = gridDim.x * blockDim.x;
    for (int e = i; e < E; e += stride) atomicAdd(&deg[load_src(ei, E, f64, e)], w[e]);
}

// ---------------- K3: temporal tables Gk[t][128], Gv[t][128] ----------------
__global__ __launch_bounds__(128)
void k_table(const float* __restrict__ Wk, const float* __restrict__ Wv,
             float* __restrict__ Gk, float* __restrict__ Gv) {
    __shared__ float te[8][128];
    int j = threadIdx.x;
    int t0 = blockIdx.x * 8;
    // freq = 200 * 10000^(-(j/2)/64)
    float freq = 200.0f * exp2f(-(float)(j >> 1) * (13.287712379549449f / 64.0f));
    bool isCos = (j & 1);
    #pragma unroll
    for (int b = 0; b < 8; ++b) {
        float t = (float)(t0 + b) * (1.0f / 4095.0f);
        float arg = t * freq;
        te[b][j] = isCos ? cosf(arg) : sinf(arg);
    }
    __syncthreads();
    int h = j >> 4, kk = j & 15;
    float ak[8] = {}, av[8] = {};
    for (int d = 0; d < 128; ++d) {
        float wk = Wk[(h * 128 + d) * 16 + kk];
        float wv = Wv[(h * 128 + d) * 16 + kk];
        float tvs[8];
        #pragma unroll
        for (int b = 0; b < 8; ++b) tvs[b] = te[b][d];
        #pragma unroll
        for (int b = 0; b < 8; ++b) { ak[b] += tvs[b] * wk; av[b] += tvs[b] * wv; }
    }
    #pragma unroll
    for (int b = 0; b < 8; ++b) {
        Gk[(size_t)(t0 + b) * 128 + j] = ak[b];
        Gv[(size_t)(t0 + b) * 128 + j] = av[b];
    }
}

// ---------------- K4: edge pass 1 — attn, exp, denominator ----------------
__global__ __launch_bounds__(256)
void k_edge1(const int* __restrict__ ei, const float* __restrict__ ewt,
             const float* __restrict__ etime, const int* __restrict__ flag,
             const float* __restrict__ deg,
             const float4* __restrict__ kn4, const float4* __restrict__ qn4,
             const float4* __restrict__ Gk4,
             float* __restrict__ exb, float* __restrict__ den, int E) {
    int gid = blockIdx.x * blockDim.x + threadIdx.x;
    int e = gid >> 5;
    if (e >= E) return;
    int lane = threadIdx.x & 31;
    int f64 = flag[0];
    int s, dd;
    load_edge(ei, E, f64, e, s, dd);
    float dg = deg[s];
    float w = ewt[e];
    float ew = dg > 0.f ? w / dg : 0.f;
    float f = etime[e] * 4095.0f;
    int i0 = (int)f;
    i0 = i0 < 0 ? 0 : (i0 > 4094 ? 4094 : i0);
    float fr = f - (float)i0;

    float4 k4 = kn4[(size_t)s * 32 + lane];
    float4 q4 = qn4[(size_t)dd * 32 + lane];
    float4 g0 = Gk4[(size_t)i0 * 32 + lane];
    float4 g1 = Gk4[(size_t)(i0 + 1) * 32 + lane];
    float kx = k4.x + g0.x + fr * (g1.x - g0.x);
    float ky = k4.y + g0.y + fr * (g1.y - g0.y);
    float kz = k4.z + g0.z + fr * (g1.z - g0.z);
    float kw = k4.w + g0.w + fr * (g1.w - g0.w);
    float p = kx * q4.x + ky * q4.y + kz * q4.z + kw * q4.w;
    p += __shfl_xor(p, 1);
    p += __shfl_xor(p, 2);
    // softmax is shift-invariant; values are O(1) so skip segment-max
    float ex = expf(p * 0.25f * ew);
    if ((lane & 3) == 0) {
        int h = lane >> 2;
        exb[(size_t)e * 8 + h] = ex;
        atomicAdd(&den[(size_t)dd * 8 + h], ex);
    }
}

// ---------------- K5: edge pass 2 — weighted V scatter ----------------
__global__ __launch_bounds__(256)
void k_edge2(const int* __restrict__ ei, const float* __restrict__ etime,
             const int* __restrict__ flag,
             const float4* __restrict__ vn4, const float4* __restrict__ Gv4,
             const float* __restrict__ exb, const float* __restrict__ den,
             float* __restrict__ out, int E) {
    int gid = blockIdx.x * blockDim.x + threadIdx.x;
    int e = gid >> 5;
    if (e >= E) return;
    int lane = threadIdx.x & 31;
    int f64 = flag[0];
    int s, dd;
    load_edge(ei, E, f64, e, s, dd);
    float f = etime[e] * 4095.0f;
    int i0 = (int)f;
    i0 = i0 < 0 ? 0 : (i0 > 4094 ? 4094 : i0);
    float fr = f - (float)i0;
    int h = lane >> 2;
    float coef = exb[(size_t)e * 8 + h] / den[(size_t)dd * 8 + h];

    float4 v4 = vn4[(size_t)s * 32 + lane];
    float4 g0 = Gv4[(size_t)i0 * 32 + lane];
    float4 g1 = Gv4[(size_t)(i0 + 1) * 32 + lane];
    float vx = (v4.x + g0.x + fr * (g1.x - g0.x)) * coef;
    float vy = (v4.y + g0.y + fr * (g1.y - g0.y)) * coef;
    float vz = (v4.z + g0.z + fr * (g1.z - g0.z)) * coef;
    float vw = (v4.w + g0.w + fr * (g1.w - g0.w)) * coef;
    float* o = out + (size_t)dd * 128 + lane * 4;
    atomicAdd(o + 0, vx);
    atomicAdd(o + 1, vy);
    atomicAdd(o + 2, vz);
    atomicAdd(o + 3, vw);
}

// ---------------- K6: out = x + gelu(aggr), in place ----------------
__global__ void k_final(const float4* __restrict__ x4, float4* __restrict__ out4, int n4) {
    int i = blockIdx.x * blockDim.x + threadIdx.x;
    if (i >= n4) return;
    float4 a = out4[i], xx = x4[i];
    a.x = xx.x + 0.5f * a.x * (1.0f + erff(a.x * 0.70710678118f));
    a.y = xx.y + 0.5f * a.y * (1.0f + erff(a.y * 0.70710678118f));
    a.z = xx.z + 0.5f * a.z * (1.0f + erff(a.z * 0.70710678118f));
    a.w = xx.w + 0.5f * a.w * (1.0f + erff(a.w * 0.70710678118f));
    out4[i] = a;
}

extern "C" void kernel_launch(void* const* d_in, const int* in_sizes, int n_in,
                              void* d_out, int out_size, void* d_ws, size_t ws_size,
                              hipStream_t stream) {
    const float* x    = (const float*)d_in[0];
    const int*   ei   = (const int*)d_in[1];
    const float* ewt  = (const float*)d_in[2];
    const float* etim = (const float*)d_in[4];
    const float* Wk   = (const float*)d_in[5];
    const float* bk   = (const float*)d_in[6];
    const float* Wq   = (const float*)d_in[7];
    const float* bq   = (const float*)d_in[8];
    const float* Wv   = (const float*)d_in[9];
    const float* bv   = (const float*)d_in[10];
    int N = in_sizes[3];
    int E = in_sizes[2];
    float* out = (float*)d_out;

    float* p = (float*)d_ws;
    float* qn  = p; p += (size_t)N * 128;
    float* kn  = p; p += (size_t)N * 128;
    float* vn  = p; p += (size_t)N * 128;
    float* deg = p; p += N;
    float* den = p; p += (size_t)N * 8;
    float* Gk  = p; p += (size_t)TBL * 128;
    float* Gv  = p; p += (size_t)TBL * 128;
    float* WT  = p; p += 384 * 128;
    float* BB  = p; p += 384;
    float* exb = p; p += (size_t)E * 8;
    int*  flag = (int*)p;

    hipMemsetAsync(deg, 0, (size_t)N * sizeof(float), stream);
    hipMemsetAsync(den, 0, (size_t)N * 8 * sizeof(float), stream);
    hipMemsetAsync(out, 0, (size_t)out_size * sizeof(float), stream);

    k_detect<<<1, 256, 0, stream>>>(ei, flag);
    k_wprep<<<64, 256, 0, stream>>>(Wq, bq, Wk, bk, Wv, bv, WT, BB);
    k_deg<<<256, 256, 0, stream>>>(ei, ewt, flag, deg, E);
    k_table<<<TBL / 8, 128, 0, stream>>>(Wk, Wv, Gk, Gv);
    k_ln_proj<<<(N + 15) / 16, 384, 0, stream>>>(x, WT, BB, qn, kn, vn, N);

    int egrid = (E * 32 + 255) / 256;
    k_edge1<<<egrid, 256, 0, stream>>>(ei, ewt, etim, flag, deg,
                                       (const float4*)kn, (const float4*)qn,
                                       (const float4*)Gk, exb, den, E);
    k_edge2<<<egrid, 256, 0, stream>>>(ei, etim, flag,
                                       (const float4*)vn, (const float4*)Gv,
                                       exb, den, out, E);
    int n4 = out_size / 4;
    k_final<<<(n4 + 255) / 256, 256, 0, stream>>>((const float4*)x, (float4*)out, n4);
}

// Round 2
// 752.220 us; speedup vs baseline: 2.3170x; 2.3170x over previous
//
#include <hip/hip_runtime.h>
#include <hip/hip_bf16.h>

constexpr int D_ = 128;
constexpr int DK_ = 16;
constexpr int TBL = 4096;

// ---------------- detect int64 vs int32 edge_index layout ----------------
__global__ void k_detect(const int* __restrict__ ei, int* __restrict__ flag) {
    __shared__ int sor;
    if (threadIdx.x == 0) sor = 0;
    __syncthreads();
    int v = 0;
    for (int k = threadIdx.x; k < 1024; k += blockDim.x) v |= ei[2 * k + 1];
    atomicOr(&sor, v);
    __syncthreads();
    if (threadIdx.x == 0) flag[0] = (sor == 0) ? 1 : 0;  // 1 => int64 layout
}

__device__ __forceinline__ void load_edge(const int* __restrict__ ei, int E, int f64,
                                          int e, int& s, int& dd) {
    if (f64) { s = ei[2 * e]; dd = ei[2 * E + 2 * e]; }
    else     { s = ei[e];     dd = ei[E + e]; }
}

// ---------------- transpose W into WT[384][128], biases into BB[384] ----------------
__global__ void k_wprep(const float* __restrict__ Wq, const float* __restrict__ bq,
                        const float* __restrict__ Wk, const float* __restrict__ bk,
                        const float* __restrict__ Wv, const float* __restrict__ bv,
                        float* __restrict__ WT, float* __restrict__ BB) {
    int idx = blockIdx.x * blockDim.x + threadIdx.x;
    int total = 384 * 128;
    for (int i = idx; i < total; i += gridDim.x * blockDim.x) {
        int c = i >> 7;
        int d = i & 127;
        int m = c >> 7;        // 0:q 1:k 2:v
        int cl = c & 127;
        int h = cl >> 4, kk = cl & 15;
        const float* W = (m == 0) ? Wq : ((m == 1) ? Wk : Wv);
        WT[i] = W[(h * D_ + d) * DK_ + kk];
    }
    if (idx < 384) {
        int m = idx >> 7, cl = idx & 127;
        const float* b = (m == 0) ? bq : ((m == 1) ? bk : bv);
        BB[idx] = b[cl];
    }
}

// ---------------- fused LayerNorm + 3 projections ----------------
__global__ __launch_bounds__(384)
void k_ln_proj(const float* __restrict__ x, const float* __restrict__ WT,
               const float* __restrict__ BB,
               float* __restrict__ qn, float* __restrict__ kn, float* __restrict__ vn,
               int N) {
    __shared__ float xs[16][128];
    int tid = threadIdx.x;
    int row0 = blockIdx.x * 16;

    for (int i = tid; i < 16 * 128; i += 384) {
        int r = i >> 7, d = i & 127;
        int gr = row0 + r;
        xs[r][d] = (gr < N) ? x[(size_t)gr * 128 + d] : 0.0f;
    }
    __syncthreads();

    if (tid < 256) {
        int r = tid >> 4, i = tid & 15;
        float v[8];
        float s = 0.f;
        #pragma unroll
        for (int k = 0; k < 8; ++k) { v[k] = xs[r][i * 8 + k]; s += v[k]; }
        s += __shfl_xor(s, 1); s += __shfl_xor(s, 2);
        s += __shfl_xor(s, 4); s += __shfl_xor(s, 8);
        float mu = s * (1.0f / 128.0f);
        float s2 = 0.f;
        #pragma unroll
        for (int k = 0; k < 8; ++k) { float dv = v[k] - mu; s2 += dv * dv; }
        s2 += __shfl_xor(s2, 1); s2 += __shfl_xor(s2, 2);
        s2 += __shfl_xor(s2, 4); s2 += __shfl_xor(s2, 8);
        float rs = rsqrtf(s2 * (1.0f / 128.0f) + 1e-5f);
        #pragma unroll
        for (int k = 0; k < 8; ++k) xs[r][i * 8 + k] = (v[k] - mu) * rs;
    }
    __syncthreads();

    int cg = tid % 96, rg = tid / 96;
    int c0 = cg * 4, r0 = rg * 4;
    float acc[4][4] = {};
    const float4* WT4 = (const float4*)WT;
    for (int d = 0; d < 128; d += 4) {
        float4 w[4];
        #pragma unroll
        for (int c = 0; c < 4; ++c) w[c] = WT4[(c0 + c) * 32 + (d >> 2)];
        #pragma unroll
        for (int r = 0; r < 4; ++r) {
            float4 xv = *(const float4*)&xs[r0 + r][d];
            #pragma unroll
            for (int c = 0; c < 4; ++c)
                acc[r][c] += xv.x * w[c].x + xv.y * w[c].y + xv.z * w[c].z + xv.w * w[c].w;
        }
    }
    #pragma unroll
    for (int c = 0; c < 4; ++c) {
        int cc = c0 + c;
        int m = cc >> 7, cl = cc & 127;
        float bb = BB[cc];
        float* dst = (m == 0) ? qn : ((m == 1) ? kn : vn);
        #pragma unroll
        for (int r = 0; r < 4; ++r) {
            int gr = row0 + r0 + r;
            if (gr < N) dst[(size_t)gr * 128 + cl] = acc[r][c] + bb;
        }
    }
}

// ---------------- degree over senders + count over receivers (one edge pass) ----------------
__global__ void k_deg_count(const int* __restrict__ ei, const float* __restrict__ w,
                            const int* __restrict__ flag, float* __restrict__ deg,
                            int* __restrict__ cnt, int E) {
    int f64 = flag[0];
    int i = blockIdx.x * blockDim.x + threadIdx.x;
    int stride = gridDim.x * blockDim.x;
    for (int e = i; e < E; e += stride) {
        int s, dd;
        load_edge(ei, E, f64, e, s, dd);
        atomicAdd(&deg[s], w[e]);
        atomicAdd(&cnt[dd], 1);
    }
}

// ---------------- temporal tables Gk[t][128], Gv[t][128] ----------------
__global__ __launch_bounds__(128)
void k_table(const float* __restrict__ Wk, const float* __restrict__ Wv,
             float* __restrict__ Gk, float* __restrict__ Gv) {
    __shared__ float te[8][128];
    int j = threadIdx.x;
    int t0 = blockIdx.x * 8;
    float freq = 200.0f * exp2f(-(float)(j >> 1) * (13.287712379549449f / 64.0f));
    bool isCos = (j & 1);
    #pragma unroll
    for (int b = 0; b < 8; ++b) {
        float t = (float)(t0 + b) * (1.0f / 4095.0f);
        float arg = t * freq;
        te[b][j] = isCos ? cosf(arg) : sinf(arg);
    }
    __syncthreads();
    int h = j >> 4, kk = j & 15;
    float ak[8] = {}, av[8] = {};
    for (int d = 0; d < 128; ++d) {
        float wk = Wk[(h * 128 + d) * 16 + kk];
        float wv = Wv[(h * 128 + d) * 16 + kk];
        float tvs[8];
        #pragma unroll
        for (int b = 0; b < 8; ++b) tvs[b] = te[b][d];
        #pragma unroll
        for (int b = 0; b < 8; ++b) { ak[b] += tvs[b] * wk; av[b] += tvs[b] * wv; }
    }
    #pragma unroll
    for (int b = 0; b < 8; ++b) {
        Gk[(size_t)(t0 + b) * 128 + j] = ak[b];
        Gv[(size_t)(t0 + b) * 128 + j] = av[b];
    }
}

// ---------------- 3-kernel exclusive scan over cnt -> rowptr ----------------
__global__ __launch_bounds__(256)
void k_scanA(const int* __restrict__ cnt, int* __restrict__ csum) {
    __shared__ int sh[256];
    int b = blockIdx.x, t = threadIdx.x;
    int base = b * 1024 + t * 4;
    int s = cnt[base] + cnt[base + 1] + cnt[base + 2] + cnt[base + 3];
    sh[t] = s;
    __syncthreads();
    for (int off = 128; off > 0; off >>= 1) {
        if (t < off) sh[t] += sh[t + off];
        __syncthreads();
    }
    if (t == 0) csum[b] = sh[0];
}

__global__ void k_scanB(int* __restrict__ csum, int nch) {
    if (blockIdx.x == 0 && threadIdx.x == 0) {
        int run = 0;
        for (int i = 0; i < nch; ++i) { int v = csum[i]; csum[i] = run; run += v; }
    }
}

__global__ __launch_bounds__(256)
void k_scanC(const int* __restrict__ cnt, const int* __restrict__ csum,
             int* __restrict__ rowptr) {
    __shared__ int sh[256];
    int b = blockIdx.x, t = threadIdx.x;
    int base = b * 1024 + t * 4;
    int v0 = cnt[base], v1 = cnt[base + 1], v2 = cnt[base + 2], v3 = cnt[base + 3];
    int tot = v0 + v1 + v2 + v3;
    sh[t] = tot;
    __syncthreads();
    for (int off = 1; off < 256; off <<= 1) {
        int add = (t >= off) ? sh[t - off] : 0;
        __syncthreads();
        sh[t] += add;
        __syncthreads();
    }
    int excl = sh[t] - tot + csum[b];
    rowptr[base]     = excl;
    rowptr[base + 1] = excl + v0;
    rowptr[base + 2] = excl + v0 + v1;
    rowptr[base + 3] = excl + v0 + v1 + v2;
}

// ---------------- scatter packed edge records into dst-CSR buckets ----------------
__global__ void k_scatter(const int* __restrict__ ei, const float* __restrict__ ewt,
                          const float* __restrict__ etime, const int* __restrict__ flag,
                          const float* __restrict__ deg, const int* __restrict__ rowptr,
                          int* __restrict__ cur, int* __restrict__ esrc,
                          float* __restrict__ eti, float* __restrict__ ewn, int E) {
    int f64 = flag[0];
    int i = blockIdx.x * blockDim.x + threadIdx.x;
    int stride = gridDim.x * blockDim.x;
    for (int e = i; e < E; e += stride) {
        int s, dd;
        load_edge(ei, E, f64, e, s, dd);
        int pos = rowptr[dd] + atomicAdd(&cur[dd], 1);
        esrc[pos] = s;
        eti[pos] = etime[e];
        float dg = deg[s];
        ewn[pos] = dg > 0.f ? ewt[e] / dg : 0.f;
    }
}

// ---------------- fused per-node attention + aggregation + residual + GELU ----------------
// one 64-lane wave per destination node; lane covers dims {2*lane, 2*lane+1}
__global__ __launch_bounds__(256)
void k_aggr(const int* __restrict__ rowptr, const int* __restrict__ esrc,
            const float* __restrict__ eti, const float* __restrict__ ewn,
            const float2* __restrict__ qn2, const float2* __restrict__ kn2,
            const float2* __restrict__ vn2,
            const float2* __restrict__ Gk2, const float2* __restrict__ Gv2,
            const float2* __restrict__ x2, float2* __restrict__ out2, int N) {
    int w = (int)((blockIdx.x * (size_t)blockDim.x + threadIdx.x) >> 6);
    if (w >= N) return;
    int lane = threadIdx.x & 63;
    float2 q = qn2[(size_t)w * 64 + lane];
    float nx = 0.f, ny = 0.f, den = 0.f;
    int beg = rowptr[w], end = rowptr[w + 1];
    for (int j = beg; j < end; ++j) {
        int src = esrc[j];
        float t = eti[j], ew = ewn[j];
        float f = t * 4095.0f;
        int i0 = (int)f;
        i0 = i0 < 0 ? 0 : (i0 > 4094 ? 4094 : i0);
        float fr = f - (float)i0;
        size_t sb = (size_t)src * 64 + lane;
        size_t tb0 = (size_t)i0 * 64 + lane;
        float2 k2 = kn2[sb];
        float2 g0 = Gk2[tb0];
        float2 g1 = Gk2[tb0 + 64];
        float kx = k2.x + g0.x + fr * (g1.x - g0.x);
        float ky = k2.y + g0.y + fr * (g1.y - g0.y);
        float p = kx * q.x + ky * q.y;
        p += __shfl_xor(p, 1);
        p += __shfl_xor(p, 2);
        p += __shfl_xor(p, 4);
        float ex = expf(p * 0.25f * ew);
        den += ex;
        float2 v2 = vn2[sb];
        float2 h0 = Gv2[tb0];
        float2 h1 = Gv2[tb0 + 64];
        nx += ex * (v2.x + h0.x + fr * (h1.x - h0.x));
        ny += ex * (v2.y + h0.y + fr * (h1.y - h0.y));
    }
    float inv = den > 0.f ? 1.0f / den : 0.f;
    nx *= inv; ny *= inv;
    float2 xx = x2[(size_t)w * 64 + lane];
    float2 o;
    o.x = xx.x + 0.5f * nx * (1.0f + erff(nx * 0.70710678118f));
    o.y = xx.y + 0.5f * ny * (1.0f + erff(ny * 0.70710678118f));
    out2[(size_t)w * 64 + lane] = o;
}

extern "C" void kernel_launch(void* const* d_in, const int* in_sizes, int n_in,
                              void* d_out, int out_size, void* d_ws, size_t ws_size,
                              hipStream_t stream) {
    const float* x    = (const float*)d_in[0];
    const int*   ei   = (const int*)d_in[1];
    const float* ewt  = (const float*)d_in[2];
    const float* etim = (const float*)d_in[4];
    const float* Wk   = (const float*)d_in[5];
    const float* bk   = (const float*)d_in[6];
    const float* Wq   = (const float*)d_in[7];
    const float* bq   = (const float*)d_in[8];
    const float* Wv   = (const float*)d_in[9];
    const float* bv   = (const float*)d_in[10];
    int N = in_sizes[3];
    int E = in_sizes[2];
    float* out = (float*)d_out;

    int NCH = (N + 1 + 1023) / 1024;    // scan chunks; scan domain NCH*1024 >= N+1
    int NP = NCH * 1024;

    float* p = (float*)d_ws;
    float* qn  = p; p += (size_t)N * 128;
    float* kn  = p; p += (size_t)N * 128;
    float* vn  = p; p += (size_t)N * 128;
    float* Gk  = p; p += (size_t)TBL * 128;
    float* Gv  = p; p += (size_t)TBL * 128;
    float* WT  = p; p += 384 * 128;
    float* BB  = p; p += 384;
    float* deg = p; p += N;
    float* eti = p; p += E;
    float* ewn = p; p += E;
    int* ip    = (int*)p;
    int* cnt    = ip; ip += NP;
    int* rowptr = ip; ip += NP;
    int* cur    = ip; ip += N;
    int* csum   = ip; ip += NCH;
    int* esrc   = ip; ip += E;
    int* flag   = ip; ip += 1;

    hipMemsetAsync(deg, 0, (size_t)N * sizeof(float), stream);
    hipMemsetAsync(cnt, 0, (size_t)NP * sizeof(int), stream);
    hipMemsetAsync(cur, 0, (size_t)N * sizeof(int), stream);

    k_detect<<<1, 256, 0, stream>>>(ei, flag);
    k_wprep<<<64, 256, 0, stream>>>(Wq, bq, Wk, bk, Wv, bv, WT, BB);
    k_deg_count<<<512, 256, 0, stream>>>(ei, ewt, flag, deg, cnt, E);
    k_table<<<TBL / 8, 128, 0, stream>>>(Wk, Wv, Gk, Gv);
    k_ln_proj<<<(N + 15) / 16, 384, 0, stream>>>(x, WT, BB, qn, kn, vn, N);

    k_scanA<<<NCH, 256, 0, stream>>>(cnt, csum);
    k_scanB<<<1, 64, 0, stream>>>(csum, NCH);
    k_scanC<<<NCH, 256, 0, stream>>>(cnt, csum, rowptr);
    k_scatter<<<512, 256, 0, stream>>>(ei, ewt, etim, flag, deg, rowptr,
                                       cur, esrc, eti, ewn, E);

    int agrid = (int)(((size_t)N * 64 + 255) / 256);
    k_aggr<<<agrid, 256, 0, stream>>>(rowptr, esrc, eti, ewn,
                                      (const float2*)qn, (const float2*)kn,
                                      (const float2*)vn,
                                      (const float2*)Gk, (const float2*)Gv,
                                      (const float2*)x, (float2*)out, N);
}

// Round 3
// 288.343 us; speedup vs baseline: 6.0445x; 2.6088x over previous
//
#include <hip/hip_runtime.h>
#include <hip/hip_bf16.h>

constexpr int D_ = 128;
constexpr int DK_ = 16;
constexpr int TBL = 4096;

typedef __attribute__((ext_vector_type(8))) short short8;
typedef __attribute__((ext_vector_type(4))) float f32x4;

__device__ __forceinline__ ushort f2b(float f) {
    uint b = __float_as_uint(f);
    uint r = (b + 0x7fffu + ((b >> 16) & 1u)) >> 16;
    return (ushort)r;
}
__device__ __forceinline__ float blo(uint u) { return __uint_as_float(u << 16); }
__device__ __forceinline__ float bhi(uint u) { return __uint_as_float(u & 0xffff0000u); }

// ---------------- detect int64 vs int32 edge_index layout ----------------
__global__ void k_detect(const int* __restrict__ ei, int* __restrict__ flag) {
    __shared__ int sor;
    if (threadIdx.x == 0) sor = 0;
    __syncthreads();
    int v = 0;
    for (int k = threadIdx.x; k < 1024; k += blockDim.x) v |= ei[2 * k + 1];
    atomicOr(&sor, v);
    __syncthreads();
    if (threadIdx.x == 0) flag[0] = (sor == 0) ? 1 : 0;  // 1 => int64 layout
}

__device__ __forceinline__ void load_edge(const int* __restrict__ ei, int E, int f64,
                                          int e, int& s, int& dd) {
    if (f64) { s = ei[2 * e]; dd = ei[2 * E + 2 * e]; }
    else     { s = ei[e];     dd = ei[E + e]; }
}

// ---------------- WTb[384][128] bf16 (B^T layout: col-major-of-B), BB[384] f32 ----------------
__global__ void k_wprep(const float* __restrict__ Wq, const float* __restrict__ bq,
                        const float* __restrict__ Wk, const float* __restrict__ bk,
                        const float* __restrict__ Wv, const float* __restrict__ bv,
                        ushort* __restrict__ WTb, float* __restrict__ BB) {
    int idx = blockIdx.x * blockDim.x + threadIdx.x;
    int total = 384 * 128;
    for (int i = idx; i < total; i += gridDim.x * blockDim.x) {
        int c = i >> 7;        // 0..383 output col (q:0-127, k:128-255, v:256-383)
        int d = i & 127;       // K index
        int m = c >> 7;
        int cl = c & 127;
        int h = cl >> 4, kk = cl & 15;
        const float* W = (m == 0) ? Wq : ((m == 1) ? Wk : Wv);
        WTb[i] = f2b(W[(h * D_ + d) * DK_ + kk]);
    }
    if (idx < 384) {
        int m = idx >> 7, cl = idx & 127;
        const float* b = (m == 0) ? bq : ((m == 1) ? bk : bv);
        BB[idx] = b[cl];
    }
}

// ---------------- LayerNorm -> bf16 xnb ----------------
__global__ __launch_bounds__(256)
void k_ln(const float2* __restrict__ x2, uint* __restrict__ xnb, int N) {
    int row = blockIdx.x * 4 + (threadIdx.x >> 6);
    if (row >= N) return;
    int lane = threadIdx.x & 63;
    float2 v = x2[(size_t)row * 64 + lane];
    float s = v.x + v.y;
    #pragma unroll
    for (int o = 1; o < 64; o <<= 1) s += __shfl_xor(s, o);
    float mu = s * (1.0f / 128.0f);
    float dx = v.x - mu, dy = v.y - mu;
    float s2 = dx * dx + dy * dy;
    #pragma unroll
    for (int o = 1; o < 64; o <<= 1) s2 += __shfl_xor(s2, o);
    float rs = rsqrtf(s2 * (1.0f / 128.0f) + 1e-5f);
    uint lo = f2b(dx * rs), hi = f2b(dy * rs);
    xnb[(size_t)row * 64 + lane] = (hi << 16) | lo;
}

// ---------------- MFMA GEMM: [N x 128] bf16 x [128 x 384] -> q/k/v bf16 ----------------
// grid: (ceil(N/128), 3); block 256 = 4 waves (2x2), wave computes 64x64
__global__ __launch_bounds__(256)
void k_gemm(const ushort* __restrict__ xnb, const ushort* __restrict__ WTb,
            const float* __restrict__ BB,
            ushort* __restrict__ qnb, ushort* __restrict__ knb, ushort* __restrict__ vnb,
            int N) {
    __shared__ short As[128 * 128];
    __shared__ short Bs[128 * 128];
    int tid = threadIdx.x;
    int rowBlk = blockIdx.x, cb = blockIdx.y;

    // stage A (xn tile) and B (WT tile), 8 passes each, XOR-swizzled LDS
    short8 av[8], bv[8];
    int chunk = tid & 15;           // 16B chunk within a 256B row
    #pragma unroll
    for (int i = 0; i < 8; ++i) {
        int row = i * 16 + (tid >> 4);
        int gRow = rowBlk * 128 + row;
        if (gRow < N) av[i] = *(const short8*)(xnb + (size_t)gRow * 128 + chunk * 8);
        else          av[i] = short8{0, 0, 0, 0, 0, 0, 0, 0};
        int gCol = cb * 128 + row;
        bv[i] = *(const short8*)(WTb + (size_t)gCol * 128 + chunk * 8);
    }
    #pragma unroll
    for (int i = 0; i < 8; ++i) {
        int row = i * 16 + (tid >> 4);
        int widx = row * 128 + ((chunk * 8) ^ ((row & 7) * 8));
        *(short8*)&As[widx] = av[i];
        *(short8*)&Bs[widx] = bv[i];
    }
    __syncthreads();

    int wv = tid >> 6, lane = tid & 63;
    int wr = wv >> 1, wc = wv & 1;
    int l15 = lane & 15, g = lane >> 4;

    f32x4 acc[4][4];
    #pragma unroll
    for (int m = 0; m < 4; ++m)
        #pragma unroll
        for (int n = 0; n < 4; ++n) acc[m][n] = f32x4{0.f, 0.f, 0.f, 0.f};

    #pragma unroll
    for (int kt = 0; kt < 4; ++kt) {
        int kshort = kt * 32 + g * 8;
        short8 af[4], bf[4];
        #pragma unroll
        for (int m = 0; m < 4; ++m) {
            int r = wr * 64 + m * 16 + l15;
            af[m] = *(const short8*)&As[r * 128 + (kshort ^ ((r & 7) * 8))];
        }
        #pragma unroll
        for (int n = 0; n < 4; ++n) {
            int c = wc * 64 + n * 16 + l15;
            bf[n] = *(const short8*)&Bs[c * 128 + (kshort ^ ((c & 7) * 8))];
        }
        #pragma unroll
        for (int m = 0; m < 4; ++m)
            #pragma unroll
            for (int n = 0; n < 4; ++n)
                acc[m][n] = __builtin_amdgcn_mfma_f32_16x16x32_bf16(af[m], bf[n], acc[m][n], 0, 0, 0);
    }

    ushort* dst = (cb == 0) ? qnb : ((cb == 1) ? knb : vnb);
    float bb[4];
    #pragma unroll
    for (int n = 0; n < 4; ++n) bb[n] = BB[cb * 128 + wc * 64 + n * 16 + l15];

    #pragma unroll
    for (int m = 0; m < 4; ++m) {
        int R0 = rowBlk * 128 + wr * 64 + m * 16 + g * 4;
        #pragma unroll
        for (int n = 0; n < 4; ++n) {
            int cl = wc * 64 + n * 16 + l15;
            #pragma unroll
            for (int r = 0; r < 4; ++r) {
                int row = R0 + r;
                if (row < N) dst[(size_t)row * 128 + cl] = f2b(acc[m][n][r] + bb[n]);
            }
        }
    }
}

// ---------------- degree over senders + count over receivers ----------------
__global__ void k_deg_count(const int* __restrict__ ei, const float* __restrict__ w,
                            const int* __restrict__ flag, float* __restrict__ deg,
                            int* __restrict__ cnt, int E) {
    int f64 = flag[0];
    int i = blockIdx.x * blockDim.x + threadIdx.x;
    int stride = gridDim.x * blockDim.x;
    for (int e = i; e < E; e += stride) {
        int s, dd;
        load_edge(ei, E, f64, e, s, dd);
        atomicAdd(&deg[s], w[e]);
        atomicAdd(&cnt[dd], 1);
    }
}

// ---------------- temporal tables -> bf16 Gkb/Gvb [TBL][128] ----------------
__global__ __launch_bounds__(128)
void k_table(const float* __restrict__ Wk, const float* __restrict__ Wv,
             ushort* __restrict__ Gkb, ushort* __restrict__ Gvb) {
    __shared__ float te[8][128];
    int j = threadIdx.x;
    int t0 = blockIdx.x * 8;
    float freq = 200.0f * exp2f(-(float)(j >> 1) * (13.287712379549449f / 64.0f));
    bool isCos = (j & 1);
    #pragma unroll
    for (int b = 0; b < 8; ++b) {
        float t = (float)(t0 + b) * (1.0f / 4095.0f);
        float arg = t * freq;
        te[b][j] = isCos ? cosf(arg) : sinf(arg);
    }
    __syncthreads();
    int h = j >> 4, kk = j & 15;
    float ak[8] = {}, av[8] = {};
    for (int d = 0; d < 128; ++d) {
        float wk = Wk[(h * 128 + d) * 16 + kk];
        float wv = Wv[(h * 128 + d) * 16 + kk];
        float tvs[8];
        #pragma unroll
        for (int b = 0; b < 8; ++b) tvs[b] = te[b][d];
        #pragma unroll
        for (int b = 0; b < 8; ++b) { ak[b] += tvs[b] * wk; av[b] += tvs[b] * wv; }
    }
    #pragma unroll
    for (int b = 0; b < 8; ++b) {
        Gkb[(size_t)(t0 + b) * 128 + j] = f2b(ak[b]);
        Gvb[(size_t)(t0 + b) * 128 + j] = f2b(av[b]);
    }
}

// ---------------- 3-kernel exclusive scan over cnt -> rowptr ----------------
__global__ __launch_bounds__(256)
void k_scanA(const int* __restrict__ cnt, int* __restrict__ csum) {
    __shared__ int sh[256];
    int b = blockIdx.x, t = threadIdx.x;
    int base = b * 1024 + t * 4;
    int s = cnt[base] + cnt[base + 1] + cnt[base + 2] + cnt[base + 3];
    sh[t] = s;
    __syncthreads();
    for (int off = 128; off > 0; off >>= 1) {
        if (t < off) sh[t] += sh[t + off];
        __syncthreads();
    }
    if (t == 0) csum[b] = sh[0];
}

__global__ void k_scanB(int* __restrict__ csum, int nch) {
    if (blockIdx.x == 0 && threadIdx.x == 0) {
        int run = 0;
        for (int i = 0; i < nch; ++i) { int v = csum[i]; csum[i] = run; run += v; }
    }
}

__global__ __launch_bounds__(256)
void k_scanC(const int* __restrict__ cnt, const int* __restrict__ csum,
             int* __restrict__ rowptr) {
    __shared__ int sh[256];
    int b = blockIdx.x, t = threadIdx.x;
    int base = b * 1024 + t * 4;
    int v0 = cnt[base], v1 = cnt[base + 1], v2 = cnt[base + 2], v3 = cnt[base + 3];
    int tot = v0 + v1 + v2 + v3;
    sh[t] = tot;
    __syncthreads();
    for (int off = 1; off < 256; off <<= 1) {
        int add = (t >= off) ? sh[t - off] : 0;
        __syncthreads();
        sh[t] += add;
        __syncthreads();
    }
    int excl = sh[t] - tot + csum[b];
    rowptr[base]     = excl;
    rowptr[base + 1] = excl + v0;
    rowptr[base + 2] = excl + v0 + v1;
    rowptr[base + 3] = excl + v0 + v1 + v2;
}

// ---------------- scatter packed edge records into dst-CSR buckets ----------------
__global__ void k_scatter(const int* __restrict__ ei, const float* __restrict__ ewt,
                          const float* __restrict__ etime, const int* __restrict__ flag,
                          const float* __restrict__ deg, const int* __restrict__ rowptr,
                          int* __restrict__ cur, int* __restrict__ esrc,
                          float* __restrict__ eti, float* __restrict__ ewn, int E) {
    int f64 = flag[0];
    int i = blockIdx.x * blockDim.x + threadIdx.x;
    int stride = gridDim.x * blockDim.x;
    for (int e = i; e < E; e += stride) {
        int s, dd;
        load_edge(ei, E, f64, e, s, dd);
        int pos = rowptr[dd] + atomicAdd(&cur[dd], 1);
        esrc[pos] = s;
        eti[pos] = etime[e];
        float dg = deg[s];
        ewn[pos] = dg > 0.f ? ewt[e] / dg : 0.f;
    }
}

// ---------------- fused per-node attention + aggregation + residual + GELU ----------------
// one 64-lane wave per destination node; lane covers dims {2*lane, 2*lane+1}; bf16 operands
__global__ __launch_bounds__(256)
void k_aggr(const int* __restrict__ rowptr, const int* __restrict__ esrc,
            const float* __restrict__ eti, const float* __restrict__ ewn,
            const ushort* __restrict__ qnb, const ushort* __restrict__ knb,
            const ushort* __restrict__ vnb,
            const ushort* __restrict__ Gkb, const ushort* __restrict__ Gvb,
            const float2* __restrict__ x2, float2* __restrict__ out2, int N) {
    int w = (int)((blockIdx.x * (size_t)blockDim.x + threadIdx.x) >> 6);
    if (w >= N) return;
    int lane = threadIdx.x & 63;
    uint qv = *(const uint*)(qnb + (size_t)w * 128 + 2 * lane);
    float qx = blo(qv), qy = bhi(qv);
    float nx = 0.f, ny = 0.f, den = 0.f;
    int beg = rowptr[w], end = rowptr[w + 1];
    for (int j = beg; j < end; ++j) {
        int src = esrc[j];
        float t = eti[j], ew = ewn[j];
        float f = t * 4095.0f;
        int i0 = (int)f;
        i0 = i0 < 0 ? 0 : (i0 > 4094 ? 4094 : i0);
        float fr = f - (float)i0;
        size_t sb = (size_t)src * 128 + 2 * lane;
        size_t tb = (size_t)i0 * 128 + 2 * lane;
        uint kv = *(const uint*)(knb + sb);
        uint g0 = *(const uint*)(Gkb + tb);
        uint g1 = *(const uint*)(Gkb + tb + 128);
        float kx = blo(kv) + blo(g0) + fr * (blo(g1) - blo(g0));
        float ky = bhi(kv) + bhi(g0) + fr * (bhi(g1) - bhi(g0));
        float p = kx * qx + ky * qy;
        p += __shfl_xor(p, 1);
        p += __shfl_xor(p, 2);
        p += __shfl_xor(p, 4);
        float ex = expf(p * 0.25f * ew);
        den += ex;
        uint vv = *(const uint*)(vnb + sb);
        uint h0 = *(const uint*)(Gvb + tb);
        uint h1 = *(const uint*)(Gvb + tb + 128);
        nx += ex * (blo(vv) + blo(h0) + fr * (blo(h1) - blo(h0)));
        ny += ex * (bhi(vv) + bhi(h0) + fr * (bhi(h1) - bhi(h0)));
    }
    float inv = den > 0.f ? 1.0f / den : 0.f;
    nx *= inv; ny *= inv;
    float2 xx = x2[(size_t)w * 64 + lane];
    float2 o;
    o.x = xx.x + 0.5f * nx * (1.0f + erff(nx * 0.70710678118f));
    o.y = xx.y + 0.5f * ny * (1.0f + erff(ny * 0.70710678118f));
    out2[(size_t)w * 64 + lane] = o;
}

extern "C" void kernel_launch(void* const* d_in, const int* in_sizes, int n_in,
                              void* d_out, int out_size, void* d_ws, size_t ws_size,
                              hipStream_t stream) {
    const float* x    = (const float*)d_in[0];
    const int*   ei   = (const int*)d_in[1];
    const float* ewt  = (const float*)d_in[2];
    const float* etim = (const float*)d_in[4];
    const float* Wk   = (const float*)d_in[5];
    const float* bk   = (const float*)d_in[6];
    const float* Wq   = (const float*)d_in[7];
    const float* bq   = (const float*)d_in[8];
    const float* Wv   = (const float*)d_in[9];
    const float* bv   = (const float*)d_in[10];
    int N = in_sizes[3];
    int E = in_sizes[2];
    float* out = (float*)d_out;

    int NCH = (N + 1 + 1023) / 1024;
    int NP = NCH * 1024;

    char* base = (char*)d_ws;
    size_t off = 0;
    auto alloc = [&](size_t bytes) {
        char* r = base + off;
        off += (bytes + 255) & ~size_t(255);
        return r;
    };
    ushort* xnb = (ushort*)alloc((size_t)N * 128 * 2);
    ushort* qnb = (ushort*)alloc((size_t)N * 128 * 2);
    ushort* knb = (ushort*)alloc((size_t)N * 128 * 2);
    ushort* vnb = (ushort*)alloc((size_t)N * 128 * 2);
    ushort* Gkb = (ushort*)alloc((size_t)TBL * 128 * 2);
    ushort* Gvb = (ushort*)alloc((size_t)TBL * 128 * 2);
    ushort* WTb = (ushort*)alloc(384 * 128 * 2);
    float*  BB  = (float*)alloc(384 * 4);
    float*  deg = (float*)alloc((size_t)N * 4);
    float*  eti = (float*)alloc((size_t)E * 4);
    float*  ewn = (float*)alloc((size_t)E * 4);
    int*    esrc = (int*)alloc((size_t)E * 4);
    int*    cnt  = (int*)alloc((size_t)NP * 4);
    int*    rowptr = (int*)alloc((size_t)NP * 4);
    int*    cur  = (int*)alloc((size_t)N * 4);
    int*    csum = (int*)alloc((size_t)NCH * 4);
    int*    flag = (int*)alloc(16);

    hipMemsetAsync(deg, 0, (size_t)N * sizeof(float), stream);
    hipMemsetAsync(cnt, 0, (size_t)NP * sizeof(int), stream);
    hipMemsetAsync(cur, 0, (size_t)N * sizeof(int), stream);

    k_detect<<<1, 256, 0, stream>>>(ei, flag);
    k_wprep<<<64, 256, 0, stream>>>(Wq, bq, Wk, bk, Wv, bv, WTb, BB);
    k_deg_count<<<512, 256, 0, stream>>>(ei, ewt, flag, deg, cnt, E);
    k_table<<<TBL / 8, 128, 0, stream>>>(Wk, Wv, Gkb, Gvb);
    k_ln<<<(N + 3) / 4, 256, 0, stream>>>((const float2*)x, (uint*)xnb, N);

    dim3 ggrid((N + 127) / 128, 3);
    k_gemm<<<ggrid, 256, 0, stream>>>(xnb, WTb, BB, qnb, knb, vnb, N);

    k_scanA<<<NCH, 256, 0, stream>>>(cnt, csum);
    k_scanB<<<1, 64, 0, stream>>>(csum, NCH);
    k_scanC<<<NCH, 256, 0, stream>>>(cnt, csum, rowptr);
    k_scatter<<<512, 256, 0, stream>>>(ei, ewt, etim, flag, deg, rowptr,
                                       cur, esrc, eti, ewn, E);

    int agrid = (int)(((size_t)N * 64 + 255) / 256);
    k_aggr<<<agrid, 256, 0, stream>>>(rowptr, esrc, eti, ewn,
                                      qnb, knb, vnb, Gkb, Gvb,
                                      (const float2*)x, (float2*)out, N);
}